// Round 1
// baseline (158.460 us; speedup 1.0000x reference)
//
#include <hip/hip_runtime.h>

typedef __attribute__((ext_vector_type(8))) short short8;   // 8 bf16 = 4 VGPRs
typedef __attribute__((ext_vector_type(4))) float floatx4;  // MFMA acc

typedef __attribute__((address_space(3))) unsigned int lds_u32;
typedef __attribute__((address_space(1))) const unsigned int glb_u32;

static __device__ __forceinline__ unsigned short f2bf(float f) {
    unsigned int u = __float_as_uint(f);
    return (unsigned short)((u + 0x7FFFu + ((u >> 16) & 1u)) >> 16);   // RNE
}
// async 16-B global->LDS DMA; LDS dest = wave-uniform base + lane*16
static __device__ __forceinline__ void cp16(const ushort* g, ushort* l) {
    __builtin_amdgcn_global_load_lds((glb_u32*)g, (lds_u32*)l, 16, 0, 0);
}

// ---- prep: weights [F][C][3] -> swizzled [12][256][64]; zero h1b pad rows ----
// blocks [0,768): w1; [768,1536): w2; [1536,1568): h1b pad rows per batch
__global__ __launch_bounds__(256)
void prep_kernel(const float* __restrict__ w1, const float* __restrict__ w2,
                 ushort* __restrict__ w1pb, ushort* __restrict__ w2pb,
                 ushort* __restrict__ h1b)
{
    const int blk = blockIdx.x, tid = threadIdx.x;
    if (blk < 1536) {
        const bool second = blk >= 768;
        const int e = (blk - (second ? 768 : 0)) * 256 + tid;
        const float* w = second ? w2 : w1;
        ushort* wpb = second ? w2pb : w1pb;
        const int f = e / 768, j = e % 768;
        const int c = j & 255, kr = j >> 8;
        const int s = j >> 6, kk = j & 63;
        wpb[s * 16384 + f * 64 + (((kk >> 3) ^ (f & 7)) << 3) + (kk & 7)]
            = f2bf(w[f * 768 + c * 3 + kr]);
    } else {
        const int b = blk - 1536;
        h1b[((size_t)b * 514 + 0)   * 256 + tid] = 0;
        h1b[((size_t)b * 514 + 513) * 256 + tid] = 0;
    }
}

// ---- conv1d(K=3) MFMA GEMM, double-buffered 2-phase pipeline ----
// Tile 32 rows x 256 cols; K=768 as 12 steps of BK=64, rotated order (rot).
// Per step: stage NEXT buffer (cp16 / f32 reg-load) -> ds_read+MFMA CURRENT ->
// (conv1: convert+ds_write A-next) -> single __syncthreads (drains vmcnt+lgkm).
// Staging latency hides under the compute phase instead of being exposed.
// conv2 grid = 1664 = 128 groups of 13: 4 conv + 9 gather interleaved so the
// HBM-write-bound gather co-resides with the latency-bound conv on every CU.
template<bool IS_CONV2>
__global__ __launch_bounds__(256, 2)
void conv_mfma_kernel(const float* __restrict__ xf,    // conv1 A source (f32 x)
                      const ushort* __restrict__ xb,   // conv2 A source (h1b bf16 padded)
                      const ushort* __restrict__ wpb,  // [12][256][64] bf16 swizzled
                      const float* __restrict__ cbias,
                      const float* __restrict__ gamma, const float* __restrict__ beta,
                      const float* __restrict__ lw, const float* __restrict__ lb,
                      ushort* __restrict__ outb,       // conv1: h1b
                      float* __restrict__ durp,        // conv2: [B][512]
                      const float* __restrict__ x,     // conv2 gather path
                      const int* __restrict__ target,
                      float* __restrict__ out0)        // [B][2304][256]
{
    __shared__ ushort As[2 * 32 * 64];    // 8 KB, double-buffered, quad-swizzled
    __shared__ ushort Bs[2 * 256 * 64];   // 64 KB, double-buffered, quad-swizzled
    __shared__ float sum_s[4][32], sq_s[4][32], mu_s[32], rs_s[32];
    __shared__ int cum[512], ps[256], sidx[64];       // gather path only

    const int tid = threadIdx.x;
    int conv_id;
    if (IS_CONV2) {
        const int grp = blockIdx.x / 13, rmod = blockIdx.x % 13;
        if (rmod >= 4) {
            // ---------- gather: 1152 blocks, 64 output rows each ----------
            const int bg = grp * 9 + (rmod - 4);
            const int b = bg / 36, t0o = (bg % 36) * 64;
            const int v0 = target[b * 512 + 2 * tid];
            const int v1 = target[b * 512 + 2 * tid + 1];
            ps[tid] = v0 + v1;
            __syncthreads();
            for (int off = 1; off < 256; off <<= 1) {
                int t = (tid >= off) ? ps[tid - off] : 0;
                __syncthreads();
                ps[tid] += t;
                __syncthreads();
            }
            const int excl = tid ? ps[tid - 1] : 0;
            cum[2 * tid]     = excl + v0;
            cum[2 * tid + 1] = excl + v0 + v1;
            __syncthreads();
            const int total = cum[511];
            if (tid < 64) {
                int t = t0o + tid;
                int lo = 0, hi = 512;
                while (lo < hi) {
                    int mid = (lo + hi) >> 1;
                    if (cum[mid] <= t) lo = mid + 1; else hi = mid;
                }
                sidx[tid] = (t < total) ? ((lo < 512) ? lo : 511) : -1;
            }
            __syncthreads();
            const float4* x4 = (const float4*)x;
            float4* o4 = (float4*)out0;
            const int lane6 = tid & 63, g4 = tid >> 6;
            #pragma unroll 4
            for (int rr = 0; rr < 16; ++rr) {
                int r = rr * 4 + g4;
                int idx = sidx[r];
                float4 v = make_float4(0.f, 0.f, 0.f, 0.f);
                if (idx >= 0) v = x4[((size_t)(b * 512 + idx)) * 64 + lane6];
                o4[((size_t)(b * 2304 + t0o + r)) * 64 + lane6] = v;
            }
            return;
        }
        conv_id = grp * 4 + rmod;
    } else {
        conv_id = blockIdx.x;
    }

    // ---------- conv path ----------
    const int w_ = tid >> 6, lane = tid & 63;
    const int q = lane >> 4, col = lane & 15;
    const int b  = conv_id & 31;                       // XCD-local batches
    const int t0 = (conv_id >> 5) << 5;
    const int rot = conv_id % 12;                      // K-step stagger

    floatx4 acc[2][4] = {};
    const int arow = tid >> 3, aquad = (tid & 7) ^ (arow & 7);
    const ushort* xbb = IS_CONV2 ? (xb + (size_t)b * 514 * 256) : (const ushort*)nullptr;
    const float*  xfb = IS_CONV2 ? (const float*)nullptr : (xf + (size_t)b * 512 * 256);

    // ---- prologue: stage step 'rot' into buffer 0 ----
    {
        const int se = rot;
        const int krow = se >> 2, cbo = (se & 3) << 6;
        const ushort* wsrc = wpb + (size_t)se * 16384 + w_ * 512 + lane * 8;
        ushort* dstB = Bs + w_ * 512;
        #pragma unroll
        for (int i = 0; i < 8; ++i) cp16(wsrc + i * 2048, dstB + i * 2048);
        if (IS_CONV2) {
            cp16(xbb + (size_t)(t0 + krow + arow) * 256 + cbo + aquad * 8, As + w_ * 512);
        } else {
            const int row = t0 + krow + arow - 1;
            float4 av0 = make_float4(0.f, 0.f, 0.f, 0.f), av1 = av0;
            if (row >= 0 && row < 512) {
                const float* px = xfb + ((size_t)row * 256 + cbo + aquad * 8);
                av0 = *(const float4*)px;
                av1 = *(const float4*)(px + 4);
            }
            short8 aval;
            aval[0] = f2bf(av0.x); aval[1] = f2bf(av0.y);
            aval[2] = f2bf(av0.z); aval[3] = f2bf(av0.w);
            aval[4] = f2bf(av1.x); aval[5] = f2bf(av1.y);
            aval[6] = f2bf(av1.z); aval[7] = f2bf(av1.w);
            *(short8*)(As + tid * 8) = aval;
        }
    }
    __syncthreads();

    int cur = 0;
    for (int s = 0; s < 12; ++s) {
        const int nb = cur ^ 1;
        float4 av0 = make_float4(0.f, 0.f, 0.f, 0.f), av1 = av0;
        if (s + 1 < 12) {
            int sn = s + 1 + rot; if (sn >= 12) sn -= 12;
            const int krow = sn >> 2, cbo = (sn & 3) << 6;
            const ushort* wsrc = wpb + (size_t)sn * 16384 + w_ * 512 + lane * 8;
            ushort* dstB = Bs + (size_t)nb * 16384 + w_ * 512;
            #pragma unroll
            for (int i = 0; i < 8; ++i) cp16(wsrc + i * 2048, dstB + i * 2048);
            if (IS_CONV2) {
                cp16(xbb + (size_t)(t0 + krow + arow) * 256 + cbo + aquad * 8,
                     As + (size_t)nb * 2048 + w_ * 512);
            } else {
                const int row = t0 + krow + arow - 1;
                if (row >= 0 && row < 512) {       // issue loads early (T14 split)
                    const float* px = xfb + ((size_t)row * 256 + cbo + aquad * 8);
                    av0 = *(const float4*)px;
                    av1 = *(const float4*)(px + 4);
                }
            }
        }
        // compute CURRENT buffer while next-step loads are in flight
        short8 af[2][2], bf[4][2];
        #pragma unroll
        for (int mi = 0; mi < 2; ++mi)
            #pragma unroll
            for (int kh = 0; kh < 2; ++kh)
                af[mi][kh] = *(const short8*)((const char*)As + cur * 4096
                    + (mi * 16 + col) * 128 + (((kh * 4 + q) ^ (col & 7)) * 16));
        #pragma unroll
        for (int ni = 0; ni < 4; ++ni)
            #pragma unroll
            for (int kh = 0; kh < 2; ++kh)
                bf[ni][kh] = *(const short8*)((const char*)Bs + cur * 32768
                    + (w_ * 64 + ni * 16 + col) * 128 + (((kh * 4 + q) ^ (col & 7)) * 16));
        #pragma unroll
        for (int kh = 0; kh < 2; ++kh)
            #pragma unroll
            for (int mi = 0; mi < 2; ++mi)
                #pragma unroll
                for (int ni = 0; ni < 4; ++ni)
                    acc[mi][ni] = __builtin_amdgcn_mfma_f32_16x16x32_bf16(
                        af[mi][kh], bf[ni][kh], acc[mi][ni], 0, 0, 0);
        if (!IS_CONV2 && s + 1 < 12) {             // convert + ds_write late
            short8 aval;
            aval[0] = f2bf(av0.x); aval[1] = f2bf(av0.y);
            aval[2] = f2bf(av0.z); aval[3] = f2bf(av0.w);
            aval[4] = f2bf(av1.x); aval[5] = f2bf(av1.y);
            aval[6] = f2bf(av1.z); aval[7] = f2bf(av1.w);
            *(short8*)(As + (size_t)nb * 2048 + tid * 8) = aval;
        }
        __syncthreads();                            // one barrier per step
        cur = nb;
    }

    // ---- epilogue: bias + per-row LN stats from registers ----
    const int base_c = w_ * 64;
    float cb4[4], gm4[4], bt4[4];
    #pragma unroll
    for (int ni = 0; ni < 4; ++ni) {
        cb4[ni] = cbias[base_c + ni * 16 + col];
        gm4[ni] = gamma[base_c + ni * 16 + col];
        bt4[ni] = beta [base_c + ni * 16 + col];
    }
    float rsum[2][4] = {}, rsq[2][4] = {};
    #pragma unroll
    for (int mi = 0; mi < 2; ++mi)
        #pragma unroll
        for (int ni = 0; ni < 4; ++ni)
            #pragma unroll
            for (int r = 0; r < 4; ++r) {
                float v = acc[mi][ni][r] + cb4[ni];
                acc[mi][ni][r] = v;
                rsum[mi][r] += v;
                rsq [mi][r] += v * v;
            }
    #pragma unroll
    for (int mi = 0; mi < 2; ++mi)
        #pragma unroll
        for (int r = 0; r < 4; ++r) {
            float s = rsum[mi][r], ss = rsq[mi][r];
            #pragma unroll
            for (int d = 8; d > 0; d >>= 1) {
                s  += __shfl_down(s,  d, 16);
                ss += __shfl_down(ss, d, 16);
            }
            if (col == 0) {
                sum_s[w_][mi * 16 + q * 4 + r] = s;
                sq_s [w_][mi * 16 + q * 4 + r] = ss;
            }
        }
    __syncthreads();
    if (tid < 32) {
        float s  = sum_s[0][tid] + sum_s[1][tid] + sum_s[2][tid] + sum_s[3][tid];
        float ss = sq_s [0][tid] + sq_s [1][tid] + sq_s [2][tid] + sq_s [3][tid];
        float mu = s * (1.f / 256.f);
        mu_s[tid] = mu;
        rs_s[tid] = rsqrtf(ss * (1.f / 256.f) - mu * mu + 1e-5f);
    }
    __syncthreads();

    if (!IS_CONV2) {
        #pragma unroll
        for (int mi = 0; mi < 2; ++mi)
            #pragma unroll
            for (int ni = 0; ni < 4; ++ni)
                #pragma unroll
                for (int r = 0; r < 4; ++r) {
                    int row = mi * 16 + q * 4 + r;
                    float v = (acc[mi][ni][r] - mu_s[row]) * rs_s[row] * gm4[ni] + bt4[ni];
                    outb[((size_t)b * 514 + t0 + row + 1) * 256 + base_c + ni * 16 + col]
                        = f2bf(fmaxf(v, 0.f));
                }
    } else {
        float lw4[4];
        #pragma unroll
        for (int ni = 0; ni < 4; ++ni) lw4[ni] = lw[base_c + ni * 16 + col];
        float dsum[2][4] = {};
        #pragma unroll
        for (int mi = 0; mi < 2; ++mi)
            #pragma unroll
            for (int ni = 0; ni < 4; ++ni)
                #pragma unroll
                for (int r = 0; r < 4; ++r) {
                    int row = mi * 16 + q * 4 + r;
                    float v = (acc[mi][ni][r] - mu_s[row]) * rs_s[row] * gm4[ni] + bt4[ni];
                    dsum[mi][r] += fmaxf(v, 0.f) * lw4[ni];
                }
        #pragma unroll
        for (int mi = 0; mi < 2; ++mi)
            #pragma unroll
            for (int r = 0; r < 4; ++r) {
                float s = dsum[mi][r];
                #pragma unroll
                for (int d = 8; d > 0; d >>= 1) s += __shfl_down(s, d, 16);
                if (col == 0) sum_s[w_][mi * 16 + q * 4 + r] = s;
            }
        __syncthreads();
        if (tid < 32)
            durp[b * 512 + t0 + tid] = fmaxf(sum_s[0][tid] + sum_s[1][tid]
                                           + sum_s[2][tid] + sum_s[3][tid] + lb[0], 0.f);
    }
}

extern "C" void kernel_launch(void* const* d_in, const int* in_sizes, int n_in,
                              void* d_out, int out_size, void* d_ws, size_t ws_size,
                              hipStream_t stream) {
    const float* x      = (const float*)d_in[0];
    const int*   target = (const int*)  d_in[1];
    const float* c1w = (const float*)d_in[3];
    const float* c1b = (const float*)d_in[4];
    const float* g1  = (const float*)d_in[5];
    const float* b1  = (const float*)d_in[6];
    const float* c2w = (const float*)d_in[7];
    const float* c2b = (const float*)d_in[8];
    const float* g2  = (const float*)d_in[9];
    const float* b2  = (const float*)d_in[10];
    const float* lw  = (const float*)d_in[11];
    const float* lb  = (const float*)d_in[12];

    const size_t PADEL = (size_t)32 * 514 * 256;
    ushort* h1b  = (ushort*)d_ws;                 // [32][514][256] bf16 padded
    ushort* w1pb = h1b + PADEL;
    ushort* w2pb = w1pb + 196608;

    float* out0 = (float*)d_out;                  // [32, 2304, 256]
    float* durp = out0 + (size_t)32 * 2304 * 256; // [32, 512]

    prep_kernel<<<1568, 256, 0, stream>>>(c1w, c2w, w1pb, w2pb, h1b);
    conv_mfma_kernel<false><<<512, 256, 0, stream>>>(
        x, nullptr, w1pb, c1b, g1, b1, nullptr, nullptr, h1b, nullptr,
        nullptr, nullptr, nullptr);
    conv_mfma_kernel<true><<<1664, 256, 0, stream>>>(
        nullptr, h1b, w2pb, c2b, g2, b2, lw, lb, nullptr, durp,
        x, target, out0);
}